// Round 1
// 246.350 us; speedup vs baseline: 1.0082x; 1.0082x over previous
//
#include <hip/hip_runtime.h>
#include <hip/hip_fp16.h>

// Problem constants: B=2, CIN=32, COUT=64, K=9, H=256, W=512, OH=256, OW=512
#define HW_IN   131072
#define W_IN    512
#define H_IN    256
#define HW_OUT  131072
#define CIN     32
#define COUT    64
#define KK      9
#define BB      2

typedef _Float16 hf2 __attribute__((ext_vector_type(2)));
typedef _Float16 hf8 __attribute__((ext_vector_type(8)));
typedef float f32x4 __attribute__((ext_vector_type(4)));

static __device__ __forceinline__ hf8 u4h(uint4 u) {
  return __builtin_bit_cast(hf8, u);
}

// ---------------------------------------------------------------------------
// Kernel 1: direct transpose x (B,CIN,H*W) fp32 -> xt (H*W, B, CIN) f16.
// R5 fix: thread = (hw, g) with g = tid&3 (16 planes/thread), so each wave
// load instruction covers 4 planes x 16 consecutive floats = 64B FULL cache
// lines (the old g=tid&7 mapping issued 32B half-line requests on all 8
// loads/thread -> ~0.9 TB/s). Stores: two 16B stores/thread at stride 32B;
// a wave's pair tiles a contiguous 8KB span (write-combined in L2).
// No LDS (R3's LDS version serialized on ds_write_u16).
// ---------------------------------------------------------------------------
__global__ __launch_bounds__(256) void transpose_direct(
    const float* __restrict__ x, _Float16* __restrict__ xt) {
  int tid = blockIdx.x * 256 + threadIdx.x;   // [0, 524288)
  int g   = tid & 3;                          // granule: planes g*16 .. g*16+15
  int hw  = tid >> 2;                         // [0, 131072)

  const float* src = x + (size_t)(g * 16) * HW_IN + hw;
  hf8 h0, h1;
#pragma unroll
  for (int c = 0; c < 8; ++c) h0[c] = (_Float16)src[(size_t)c * HW_IN];
#pragma unroll
  for (int c = 0; c < 8; ++c) h1[c] = (_Float16)src[(size_t)(c + 8) * HW_IN];
  _Float16* dst = xt + (size_t)hw * 64 + g * 16;
  *(hf8*)(dst)     = h0;
  *(hf8*)(dst + 8) = h1;
}

// ---------------------------------------------------------------------------
// Kernel 2: fused gather + MFMA contraction — unchanged R2-best config.
// Pinned at ~3.6 TB/s random L2-fill (FETCH 477MB vs 604MB demand = ~21% L2
// hit, consistent with 4MB/XCD L2 over a uniformly-random 16MB working set).
// GEMM view: out[pix, o] = sum_{ck=k*32+c} samp[pix, ck] * W[o, ck].
// One wave = 16 pixels x 64 couts (4 N-tiles), K=288 = 9 taps x 32 channels.
// ---------------------------------------------------------------------------
__global__ __launch_bounds__(256, 4) void mapped_conv_mfma(
    const _Float16* __restrict__ xt,
    const float* __restrict__ weight,   // [COUT][CIN][KK] fp32
    const float* __restrict__ bias,     // [COUT]
    const float* __restrict__ sm,       // [HW_OUT][KK][2] fp32
    float* __restrict__ out) {          // [BB][COUT][HW_OUT] fp32
  __shared__ __align__(16) _Float16 w_lds[KK * COUT * CIN];  // 36 KB

  int t = threadIdx.x;
  // Stage weights: w_lds[(k*64 + o)*32 + c] = W[o][c][k] as f16.
  for (int j = t; j < COUT * CIN * KK; j += 256) {
    unsigned ju = (unsigned)j;
    unsigned o  = ju / 288u;
    unsigned rr = ju % 288u;
    unsigned c  = rr / 9u;
    unsigned k  = rr % 9u;
    w_lds[(k * 64u + o) * 32u + c] = (_Float16)weight[ju];
  }
  __syncthreads();

  int wave = t >> 6;
  int lane = t & 63;
  int m    = lane & 15;   // A-row: pixel; B-col: cout within N-tile
  int quad = lane >> 4;   // channel quarter (A) / k-chunk (B) / row group (C)

  int pix_base = blockIdx.x * 64 + wave * 16;     // 4096 blocks x 4 waves
  int pix  = pix_base + m;
  int b    = pix_base >> 17;                      // wave-uniform
  int hw   = pix & (HW_OUT - 1);
  int hw_base = pix_base & (HW_OUT - 1);

  const uint4* xt4 = (const uint4*)xt;
  int bq = b * 4 + quad;   // uint4-granule within a pixel's 64 halves

  f32x4 acc[4] = {{0.f,0.f,0.f,0.f},{0.f,0.f,0.f,0.f},
                  {0.f,0.f,0.f,0.f},{0.f,0.f,0.f,0.f}};

  const float* smp = sm + (size_t)hw * (KK * 2);
  const uint4* wbl = (const uint4*)w_lds + (size_t)(m * 4 + quad);

#pragma unroll 3
  for (int k = 0; k < KK; ++k) {
    float sx = smp[k * 2 + 0];
    float sy = smp[k * 2 + 1];
    float bxf = floorf(sx), byf = floorf(sy);
    float fx = sx - bxf, fy = sy - byf;
    int ix0 = (int)bxf, iy0 = (int)byf;
    int ix1 = min(ix0 + 1, W_IN - 1);
    int iy1 = min(iy0 + 1, H_IN - 1);
    ix0 = max(min(ix0, W_IN - 1), 0); ix1 = max(ix1, 0);
    iy0 = max(min(iy0, H_IN - 1), 0); iy1 = max(iy1, 0);

    uint4 v00 = xt4[(iy0 * W_IN + ix0) * 8 + bq];
    uint4 v01 = xt4[(iy0 * W_IN + ix1) * 8 + bq];
    uint4 v10 = xt4[(iy1 * W_IN + ix0) * 8 + bq];
    uint4 v11 = xt4[(iy1 * W_IN + ix1) * 8 + bq];

    _Float16 w00 = (_Float16)((1.f - fx) * (1.f - fy));
    _Float16 w01 = (_Float16)(fx * (1.f - fy));
    _Float16 w10 = (_Float16)((1.f - fx) * fy);
    _Float16 w11 = (_Float16)(fx * fy);
    hf8 h00 = {w00, w00, w00, w00, w00, w00, w00, w00};
    hf8 h01 = {w01, w01, w01, w01, w01, w01, w01, w01};
    hf8 h10 = {w10, w10, w10, w10, w10, w10, w10, w10};
    hf8 h11 = {w11, w11, w11, w11, w11, w11, w11, w11};

    hf8 a = h00 * u4h(v00) + h01 * u4h(v01) + h10 * u4h(v10) + h11 * u4h(v11);

    const uint4* wk = wbl + (size_t)k * 256;   // per-k block = 64 o * 4 granules
    hf8 b0 = u4h(wk[0]);
    hf8 b1 = u4h(wk[64]);
    hf8 b2 = u4h(wk[128]);
    hf8 b3 = u4h(wk[192]);

    acc[0] = __builtin_amdgcn_mfma_f32_16x16x32_f16(a, b0, acc[0], 0, 0, 0);
    acc[1] = __builtin_amdgcn_mfma_f32_16x16x32_f16(a, b1, acc[1], 0, 0, 0);
    acc[2] = __builtin_amdgcn_mfma_f32_16x16x32_f16(a, b2, acc[2], 0, 0, 0);
    acc[3] = __builtin_amdgcn_mfma_f32_16x16x32_f16(a, b3, acc[3], 0, 0, 0);
  }

  // Epilogue: lane writes 4 consecutive pixels (rows quad*4..+3) for cout n.
  int hw0 = hw_base + quad * 4;
#pragma unroll
  for (int nt = 0; nt < 4; ++nt) {
    int n = nt * 16 + m;
    float bn = bias[n];
    float4 v = make_float4(acc[nt][0] + bn, acc[nt][1] + bn,
                           acc[nt][2] + bn, acc[nt][3] + bn);
    float* op = out + (size_t)(b * COUT + n) * HW_OUT + hw0;
    *(float4*)op = v;
  }
}

extern "C" void kernel_launch(void* const* d_in, const int* in_sizes, int n_in,
                              void* d_out, int out_size, void* d_ws, size_t ws_size,
                              hipStream_t stream) {
  const float* x  = (const float*)d_in[0];   // [B][CIN][H*W]
  const float* w  = (const float*)d_in[1];   // [COUT][CIN][KK]
  const float* bs = (const float*)d_in[2];   // [COUT]
  const float* sm = (const float*)d_in[3];   // [OH*OW][KK][2]
  float* out = (float*)d_out;                // [B][COUT][OH*OW]
  _Float16* xt = (_Float16*)d_ws;            // 16 MB scratch: (H*W, B, CIN) f16

  transpose_direct<<<dim3(2048), dim3(256), 0, stream>>>(x, xt);
  mapped_conv_mfma<<<dim3(4096), dim3(256), 0, stream>>>(xt, w, bs, sm, out);
}

// Round 2
// 241.077 us; speedup vs baseline: 1.0303x; 1.0219x over previous
//
#include <hip/hip_runtime.h>
#include <hip/hip_fp16.h>

// Problem constants: B=2, CIN=32, COUT=64, K=9, H=256, W=512, OH=256, OW=512
#define HW_IN   131072
#define W_IN    512
#define H_IN    256
#define HW_OUT  131072
#define CIN     32
#define COUT    64
#define KK      9
#define BB      2

typedef _Float16 hf2 __attribute__((ext_vector_type(2)));
typedef _Float16 hf4 __attribute__((ext_vector_type(4)));
typedef _Float16 hf8 __attribute__((ext_vector_type(8)));
typedef float f32x4 __attribute__((ext_vector_type(4)));

static __device__ __forceinline__ hf8 u4h(uint4 u) {
  return __builtin_bit_cast(hf8, u);
}

// ---------------------------------------------------------------------------
// Kernel 1: transpose x (B,CIN,H*W) fp32 -> xt (H*W, B, CIN) f16, via LDS.
// R6 theory: all previous direct variants read planes at stride 512KB
// (power of 2) -> channel/L2-slice select bits (low addr bits) are identical
// across the 8-16 plane streams, so each wave's whole 1KB instruction lands
// on 1-2 channels -> ~0.5 TB/s. Fix: each wave-instruction reads a 1KB
// CONTIGUOUS span of ONE plane (spans >=4 channels, same pattern as a 6.3TB/s
// streaming copy) and the transpose happens in LDS.
// LDS cost is negligible by construction (unlike R3's ds_write_u16 scatter):
//   phase-1 writes: lane-contiguous b64, conflict-free.
//   phase-2 reads: 64 x u16/thread, <=4-way conflicts (row pad to 260 f16),
//   ~0.5us aggregate vs ~8us DRAM floor.
//   phase-2 stores: 8 pixels x 128B = 1KB contiguous per wave-instruction.
// ---------------------------------------------------------------------------
__global__ __launch_bounds__(256) void transpose_lds(
    const float* __restrict__ x, _Float16* __restrict__ xt) {
  __shared__ _Float16 lt[64][260];   // 33.3 KB, row stride 520B (8B-aligned)
  int t = threadIdx.x;
  int wave = t >> 6, lane = t & 63;
  int hwbase = blockIdx.x * 256;

  // Phase 1: 64 plane-rows of 256 floats; wave w takes planes {i*4+w}.
#pragma unroll
  for (int i = 0; i < 16; ++i) {
    int p = i * 4 + wave;
    f32x4 v = *((const f32x4*)(x + (size_t)p * HW_IN + hwbase) + lane);
    hf4 h;
    h[0] = (_Float16)v[0]; h[1] = (_Float16)v[1];
    h[2] = (_Float16)v[2]; h[3] = (_Float16)v[3];
    *(hf4*)&lt[p][lane * 4] = h;
  }
  __syncthreads();

  // Phase 2: thread t -> granule gg (8 channels) of pixel hwl; wave writes
  // 8 consecutive pixels' full 128B records = 1KB contiguous per store.
  int gg  = t & 7;
  int hl0 = t >> 3;
#pragma unroll
  for (int j = 0; j < 8; ++j) {
    int hwl = hl0 + j * 32;
    hf8 h;
#pragma unroll
    for (int c = 0; c < 8; ++c) h[c] = lt[gg * 8 + c][hwl];
    *(hf8*)(xt + (size_t)(hwbase + hwl) * 64 + gg * 8) = h;
  }
}

// ---------------------------------------------------------------------------
// Kernel 2: fused gather + MFMA contraction — unchanged R2-best config.
// Pinned at ~3.6 TB/s random L2-fill (FETCH 477MB vs 604MB demand = ~21% L2
// hit, consistent with 4MB/XCD L2 over a uniformly-random 16MB working set).
// GEMM view: out[pix, o] = sum_{ck=k*32+c} samp[pix, ck] * W[o, ck].
// One wave = 16 pixels x 64 couts (4 N-tiles), K=288 = 9 taps x 32 channels.
// ---------------------------------------------------------------------------
__global__ __launch_bounds__(256, 4) void mapped_conv_mfma(
    const _Float16* __restrict__ xt,
    const float* __restrict__ weight,   // [COUT][CIN][KK] fp32
    const float* __restrict__ bias,     // [COUT]
    const float* __restrict__ sm,       // [HW_OUT][KK][2] fp32
    float* __restrict__ out) {          // [BB][COUT][HW_OUT] fp32
  __shared__ __align__(16) _Float16 w_lds[KK * COUT * CIN];  // 36 KB

  int t = threadIdx.x;
  // Stage weights: w_lds[(k*64 + o)*32 + c] = W[o][c][k] as f16.
  for (int j = t; j < COUT * CIN * KK; j += 256) {
    unsigned ju = (unsigned)j;
    unsigned o  = ju / 288u;
    unsigned rr = ju % 288u;
    unsigned c  = rr / 9u;
    unsigned k  = rr % 9u;
    w_lds[(k * 64u + o) * 32u + c] = (_Float16)weight[ju];
  }
  __syncthreads();

  int wave = t >> 6;
  int lane = t & 63;
  int m    = lane & 15;   // A-row: pixel; B-col: cout within N-tile
  int quad = lane >> 4;   // channel quarter (A) / k-chunk (B) / row group (C)

  int pix_base = blockIdx.x * 64 + wave * 16;     // 4096 blocks x 4 waves
  int pix  = pix_base + m;
  int b    = pix_base >> 17;                      // wave-uniform
  int hw   = pix & (HW_OUT - 1);
  int hw_base = pix_base & (HW_OUT - 1);

  const uint4* xt4 = (const uint4*)xt;
  int bq = b * 4 + quad;   // uint4-granule within a pixel's 64 halves

  f32x4 acc[4] = {{0.f,0.f,0.f,0.f},{0.f,0.f,0.f,0.f},
                  {0.f,0.f,0.f,0.f},{0.f,0.f,0.f,0.f}};

  const float* smp = sm + (size_t)hw * (KK * 2);
  const uint4* wbl = (const uint4*)w_lds + (size_t)(m * 4 + quad);

#pragma unroll 3
  for (int k = 0; k < KK; ++k) {
    float sx = smp[k * 2 + 0];
    float sy = smp[k * 2 + 1];
    float bxf = floorf(sx), byf = floorf(sy);
    float fx = sx - bxf, fy = sy - byf;
    int ix0 = (int)bxf, iy0 = (int)byf;
    int ix1 = min(ix0 + 1, W_IN - 1);
    int iy1 = min(iy0 + 1, H_IN - 1);
    ix0 = max(min(ix0, W_IN - 1), 0); ix1 = max(ix1, 0);
    iy0 = max(min(iy0, H_IN - 1), 0); iy1 = max(iy1, 0);

    uint4 v00 = xt4[(iy0 * W_IN + ix0) * 8 + bq];
    uint4 v01 = xt4[(iy0 * W_IN + ix1) * 8 + bq];
    uint4 v10 = xt4[(iy1 * W_IN + ix0) * 8 + bq];
    uint4 v11 = xt4[(iy1 * W_IN + ix1) * 8 + bq];

    _Float16 w00 = (_Float16)((1.f - fx) * (1.f - fy));
    _Float16 w01 = (_Float16)(fx * (1.f - fy));
    _Float16 w10 = (_Float16)((1.f - fx) * fy);
    _Float16 w11 = (_Float16)(fx * fy);
    hf8 h00 = {w00, w00, w00, w00, w00, w00, w00, w00};
    hf8 h01 = {w01, w01, w01, w01, w01, w01, w01, w01};
    hf8 h10 = {w10, w10, w10, w10, w10, w10, w10, w10};
    hf8 h11 = {w11, w11, w11, w11, w11, w11, w11, w11};

    hf8 a = h00 * u4h(v00) + h01 * u4h(v01) + h10 * u4h(v10) + h11 * u4h(v11);

    const uint4* wk = wbl + (size_t)k * 256;   // per-k block = 64 o * 4 granules
    hf8 b0 = u4h(wk[0]);
    hf8 b1 = u4h(wk[64]);
    hf8 b2 = u4h(wk[128]);
    hf8 b3 = u4h(wk[192]);

    acc[0] = __builtin_amdgcn_mfma_f32_16x16x32_f16(a, b0, acc[0], 0, 0, 0);
    acc[1] = __builtin_amdgcn_mfma_f32_16x16x32_f16(a, b1, acc[1], 0, 0, 0);
    acc[2] = __builtin_amdgcn_mfma_f32_16x16x32_f16(a, b2, acc[2], 0, 0, 0);
    acc[3] = __builtin_amdgcn_mfma_f32_16x16x32_f16(a, b3, acc[3], 0, 0, 0);
  }

  // Epilogue: lane writes 4 consecutive pixels (rows quad*4..+3) for cout n.
  int hw0 = hw_base + quad * 4;
#pragma unroll
  for (int nt = 0; nt < 4; ++nt) {
    int n = nt * 16 + m;
    float bn = bias[n];
    float4 v = make_float4(acc[nt][0] + bn, acc[nt][1] + bn,
                           acc[nt][2] + bn, acc[nt][3] + bn);
    float* op = out + (size_t)(b * COUT + n) * HW_OUT + hw0;
    *(float4*)op = v;
  }
}

extern "C" void kernel_launch(void* const* d_in, const int* in_sizes, int n_in,
                              void* d_out, int out_size, void* d_ws, size_t ws_size,
                              hipStream_t stream) {
  const float* x  = (const float*)d_in[0];   // [B][CIN][H*W]
  const float* w  = (const float*)d_in[1];   // [COUT][CIN][KK]
  const float* bs = (const float*)d_in[2];   // [COUT]
  const float* sm = (const float*)d_in[3];   // [OH*OW][KK][2]
  float* out = (float*)d_out;                // [B][COUT][OH*OW]
  _Float16* xt = (_Float16*)d_ws;            // 16 MB scratch: (H*W, B, CIN) f16

  transpose_lds<<<dim3(512), dim3(256), 0, stream>>>(x, xt);
  mapped_conv_mfma<<<dim3(4096), dim3(256), 0, stream>>>(xt, w, bs, sm, out);
}